// Round 13
// baseline (933.261 us; speedup 1.0000x reference)
//
#include <hip/hip_runtime.h>
#include <stdint.h>

// Experts MLP: out[b,e] = gelu(x[b,e] @ w1[e] + b1[e]) @ w2[e] + b2[e]
// B=4 E=8 N=1024 D=1024 H=4096.
// Round 13: reads-in-flight-during-MFMA. Each interval: [reads for a FUTURE
// cluster; sched_barrier(0); setprio+16 MFMA; stage; counted vmcnt; bar].
// No lgkm drains (r12's pins made the LDS port idle under every cluster ->
// 2304+2483 serialized = the 5400cyc/tile plateau of r4-r12). Compiler emits
// counted lgkm (8..12) before each cluster, leaving the new batch in flight.
// Spill-proofing (r9 lesson): frags 96 VGPR (afC/afN + bfX/bfY ping-pong),
// addressing slimmed to 2 base pointers + compile-time 64*K offsets.

typedef __attribute__((ext_vector_type(8))) short short8;
typedef __attribute__((ext_vector_type(4))) float f32x4;

__device__ __forceinline__ unsigned short f2b(float f){
  union { float f; unsigned int u; } v; v.f = f;
  unsigned int r = v.u + 0x7fffu + ((v.u >> 16) & 1u);   // RNE
  return (unsigned short)(r >> 16);
}

// tanh-form GELU via exp2/rcp (verified r3-r12)
__device__ __forceinline__ float gelu_fast(float v){
  float v2 = v * v;
  float w = v * (-2.302217529693f + -0.102943795894f * v2);
  float e = __builtin_amdgcn_exp2f(w);
  return v * __builtin_amdgcn_rcpf(1.0f + e);
}

__device__ __forceinline__ void glds16(const void* g, const void* l){
  __builtin_amdgcn_global_load_lds((const __attribute__((address_space(1))) uint32_t*)g,
                                   (__attribute__((address_space(3))) uint32_t*)l, 16, 0, 0);
}

#define BAR() do{ asm volatile("" ::: "memory"); __builtin_amdgcn_s_barrier(); asm volatile("" ::: "memory"); }while(0)
#define VMW(N) do{ if ((N)==4) asm volatile("s_waitcnt vmcnt(4)":::"memory"); \
  else if ((N)==2) asm volatile("s_waitcnt vmcnt(2)":::"memory"); \
  else if ((N)==0) asm volatile("s_waitcnt vmcnt(0)":::"memory"); }while(0)
#define SCHEDPIN() __builtin_amdgcn_sched_barrier(0)

// ---------------- prep kernels (verified r1-r12) ----------------

__global__ void cvt_x_kernel(const float* __restrict__ src, unsigned short* __restrict__ dst, int n4){
  int i = blockIdx.x * blockDim.x + threadIdx.x;
  int stride = gridDim.x * blockDim.x;
  for (; i < n4; i += stride){
    float4 v = ((const float4*)src)[i];
    ushort4 o;
    o.x = f2b(v.x); o.y = f2b(v.y); o.z = f2b(v.z); o.w = f2b(v.w);
    ((ushort4*)dst)[i] = o;
  }
}

__global__ void transpose_cvt(const float* __restrict__ src, unsigned short* __restrict__ dst, int R, int C){
  __shared__ float t[64][65];
  const int e = blockIdx.z;
  src += (size_t)e * R * C;
  dst += (size_t)e * R * C;
  const int r0 = blockIdx.y * 64, c0 = blockIdx.x * 64;
  const int tid = threadIdx.x;
  const int lr = tid >> 4;
  const int lc4 = (tid & 15) * 4;
  #pragma unroll
  for (int p2 = 0; p2 < 4; p2++){
    int r = lr + p2 * 16;
    float4 v = *(const float4*)(src + (size_t)(r0 + r) * C + (c0 + lc4));
    t[r][lc4+0] = v.x; t[r][lc4+1] = v.y; t[r][lc4+2] = v.z; t[r][lc4+3] = v.w;
  }
  __syncthreads();
  #pragma unroll
  for (int p2 = 0; p2 < 4; p2++){
    int c = lr + p2 * 16;
    ushort4 o;
    o.x = f2b(t[lc4+0][c]); o.y = f2b(t[lc4+1][c]);
    o.z = f2b(t[lc4+2][c]); o.w = f2b(t[lc4+3][c]);
    *(ushort4*)(dst + (size_t)(c0 + c) * R + (r0 + lc4)) = o;
  }
}

// ---------------- 256x256 GEMM, LDS-port-under-MFMA schedule ----------------
// LDS rows = 64 bf16 (8 x 16B chunks); chunk c of row r at LDS chunk
// (c ^ (r&7)); LDS linear + pre-swizzled global source (rule #21).
// LDS map (shorts): A buf0 @0, A buf1 @16384, B buf0 @32768, B buf1 @49152.
// Per tile kt (buf p = kt&1), quadrants q00,q01,q11,q10:
//  I0: read bf1(kt)(4) + afN<-A-hi(kt)(8);  q00(afC,BF0);  stage B-lo(kt+1)
//  I1: (no reads - absorbs I0 port backlog); q01(afC,BF1); stage B-hi(kt+1); vmcnt(4)
//  I2: read afC<-A-lo(kt+1)(8) [other buf];  q11(afN,BF1); stage A-hi(kt+1); vmcnt(4)
//  I3: read BF1<-bf0(kt+1)(4) [other buf];   q10(afN,BF0); stage A-lo(kt+2)->CURRENT buf; vmcnt(2)
// Steady in-flight entering a tile: {A-lo(kt+1)x2}. vmcnt(4)@I1 drains it
// (needed by I2's read-ahead); vmcnt(4)@I2 drains B-lo(kt+1) (I3's read);
// vmcnt(2)@I3 drains B-hi+A-hi(kt+1) (next I0's reads), keeps A-lo(kt+2).
// B arrays ping-pong roles per tile parity (bf0(kt+1) lands in bf1(kt)'s
// dead regs). afC always holds A-lo, afN always A-hi.

template<int PHASE1>
__global__ __launch_bounds__(512, 2) void gemm256(
    const unsigned short* __restrict__ A,
    const unsigned short* __restrict__ Bt,
    const float* __restrict__ bias,
    void* __restrict__ Out,
    int p0)
{
  constexpr int M  = 1024;
  constexpr int K  = PHASE1 ? 1024 : 4096;
  constexpr int Nd = PHASE1 ? 4096 : 1024;
  constexpr int TM = M / 256, TN = Nd / 256;
  constexpr int NT = K / 64;                 // 16 or 64 (even, >=4)
  constexpr size_t RB = (size_t)64 * K;      // row-block stride (elems)

  const int cpx = gridDim.x >> 3;
  const int bid = (blockIdx.x & 7) * cpx + (blockIdx.x >> 3);
  const int tn = bid % TN;
  const int t2 = bid / TN;
  const int tm = t2 % TM;
  const int cp = t2 / TM;
  const int p  = p0 + cp, e = p & 7;
  const int m0 = tm * 256, n0 = tn * 256;

  const unsigned short* Ag = A  + (size_t)(PHASE1 ? p : cp) * M * K + (size_t)m0 * K;
  const unsigned short* Bg = Bt + (size_t)e * Nd * K + (size_t)n0 * K;
  const float*          bp = bias + (size_t)e * Nd;

  __shared__ __align__(16) unsigned short lds[65536];

  const int tid = threadIdx.x;
  const int w = tid >> 6, lane = tid & 63;
  const int wr = w >> 2, wc = w & 3;          // 2 x 4 waves; wave tile 128 x 64
  const int c15 = lane & 15, q = lane >> 4;

  // staging: 2 base pointers only; row-block offsets are compile-time (RB)
  const int trow = (w << 3) + (lane >> 3);                 // 0..63
  const int scol = ((lane & 7) ^ (trow & 7)) << 3;
  const unsigned short* pA = Ag + (size_t)trow * K + scol;
  const unsigned short* pB = Bg + (size_t)trow * K + scol;
  const int wof = w << 9;                                  // LDS dest base (shorts)

  // frag-read per-thread constants (shorts)
  const int rA64 = (wr * 128 + c15) << 6;
  const int rB64 = (wc * 64  + c15) << 6;
  const int cx0 = ( q      ^ (c15 & 7)) << 3;              // kk=0 chunk
  const int cx1 = ((q ^ 4) ^ (c15 & 7)) << 3;              // kk=1 chunk

  // bias folded into accumulator init (bv dead after init)
  float bv[4];
  #pragma unroll
  for (int nf = 0; nf < 4; ++nf) bv[nf] = bp[n0 + wc * 64 + nf * 16 + c15];

  f32x4 acc[8][4];
  #pragma unroll
  for (int i = 0; i < 8; i++)
    #pragma unroll
    for (int j = 0; j < 4; j++) acc[i][j] = (f32x4)(bv[j]);

  short8 afC[4][2], afN[4][2], bfX[2][2], bfY[2][2];

#define LDS8(OFS) (*(const short8*)(lds + (OFS)))
#define RD_A(DST, BASE) do{ _Pragma("unroll") for (int mf = 0; mf < 4; ++mf){ \
    DST[mf][0] = LDS8((BASE) + rA64 + mf * 1024 + cx0); \
    DST[mf][1] = LDS8((BASE) + rA64 + mf * 1024 + cx1); } }while(0)
#define RD_B(DST, BASE) do{ _Pragma("unroll") for (int nf = 0; nf < 2; ++nf){ \
    DST[nf][0] = LDS8((BASE) + rB64 + nf * 1024 + cx0); \
    DST[nf][1] = LDS8((BASE) + rB64 + nf * 1024 + cx1); } }while(0)
#define Q8(MO,NO,AF,BF) do{ _Pragma("unroll") for (int mi = 0; mi < 4; ++mi) \
    _Pragma("unroll") for (int nf = 0; nf < 2; ++nf){ \
      acc[(MO)+mi][(NO)+nf] = __builtin_amdgcn_mfma_f32_16x16x32_bf16(AF[mi][0], BF[nf][0], acc[(MO)+mi][(NO)+nf], 0, 0, 0); \
      acc[(MO)+mi][(NO)+nf] = __builtin_amdgcn_mfma_f32_16x16x32_bf16(AF[mi][1], BF[nf][1], acc[(MO)+mi][(NO)+nf], 0, 0, 0); } }while(0)

  // ---- prologue: tile0 (A+B) into buf0; A-lo(1) into buf1; preload frags ----
  glds16(pA,               lds + wof);
  glds16(pA + RB,          lds + wof + 4096);
  glds16(pA + 2*RB,        lds + wof + 8192);
  glds16(pA + 3*RB,        lds + wof + 12288);
  glds16(pB,               lds + wof + 32768);
  glds16(pB + RB,          lds + wof + 32768 + 4096);
  glds16(pB + 2*RB,        lds + wof + 32768 + 8192);
  glds16(pB + 3*RB,        lds + wof + 32768 + 12288);
  glds16(pA + 64,          lds + wof + 16384);           // A-lo(1) rows 0-63
  glds16(pA + 2*RB + 64,   lds + wof + 16384 + 8192);    // A-lo(1) rows 128-191
  VMW(2);                        // drain tile0; keep A-lo(1) in flight
  BAR();
  RD_A(afC, 0);                  // afL(0)
  RD_B(bfX, 32768);              // bf0(0)

  // One K-tile. BF0 holds bf0(kt); BF1 gets bf1(kt) then bf0(kt+1).
  // STG: stage B(kt+1)+A-hi(kt+1). SA2: stage A-lo(kt+2). RDA/RDB: read-ahead
  // afC<-A-lo(kt+1) / BF1<-bf0(kt+1). W1/W2/W3: vmcnt at I1/I2/I3 ends.
#define TILE_F(CB, BF0, BF1, STG, SA2, RDA, RDB, W1, W2, W3) do{                \
    constexpr int AB  = (CB) * 16384;                                           \
    constexpr int BB  = 32768 + (CB) * 16384;                                   \
    constexpr int ABn = ((CB) ^ 1) * 16384;                                     \
    constexpr int BBn = 32768 + (((CB) ^ 1) * 16384);                           \
    constexpr int O1  = (CB) ? 128 : 64;                                        \
    constexpr int O2  = (CB) ? 192 : 128;                                       \
    /* I0: read bf1(kt) + afN<-A-hi(kt); q00; stage B-lo(kt+1) */               \
    RD_B(BF1, BB + 2048);                                                       \
    RD_A(afN, AB + 4096);                                                       \
    SCHEDPIN();                                                                 \
    __builtin_amdgcn_s_setprio(1);                                              \
    Q8(0, 0, afC, BF0);                                                         \
    __builtin_amdgcn_s_setprio(0);                                              \
    if (STG){ glds16(pB + O1,      lds + BBn + wof);                            \
              glds16(pB + RB + O1, lds + BBn + 4096 + wof); }                   \
    BAR();                                                                      \
    /* I1: no reads (absorbs I0 port backlog); q01; stage B-hi(kt+1) */         \
    __builtin_amdgcn_s_setprio(1);                                              \
    Q8(0, 2, afC, BF1);                                                         \
    __builtin_amdgcn_s_setprio(0);                                              \
    if (STG){ glds16(pB + 2*RB + O1, lds + BBn + 8192 + wof);                   \
              glds16(pB + 3*RB + O1, lds + BBn + 12288 + wof); }                \
    if ((W1) >= 0) VMW(W1);                                                     \
    BAR();                                                                      \
    /* I2: read afC<-A-lo(kt+1) [other buf]; q11; stage A-hi(kt+1) */           \
    if (RDA){ RD_A(afC, ABn); }                                                 \
    SCHEDPIN();                                                                 \
    __builtin_amdgcn_s_setprio(1);                                              \
    Q8(4, 2, afN, BF1);                                                         \
    __builtin_amdgcn_s_setprio(0);                                              \
    if (STG){ glds16(pA + RB + O1,   lds + ABn + 4096 + wof);                   \
              glds16(pA + 3*RB + O1, lds + ABn + 12288 + wof); }                \
    if ((W2) >= 0) VMW(W2);                                                     \
    BAR();                                                                      \
    /* I3: read BF1<-bf0(kt+1) [other buf]; q10; stage A-lo(kt+2)->CURRENT */   \
    if (RDB){ RD_B(BF1, BBn); }                                                 \
    SCHEDPIN();                                                                 \
    __builtin_amdgcn_s_setprio(1);                                              \
    Q8(4, 0, afN, BF0);                                                         \
    __builtin_amdgcn_s_setprio(0);                                              \
    if (SA2){ glds16(pA + O2,        lds + AB + wof);                           \
              glds16(pA + 2*RB + O2, lds + AB + 8192 + wof); }                  \
    if ((W3) >= 0) VMW(W3);                                                     \
    BAR();                                                                      \
  }while(0)

  for (int kt2 = 0; kt2 < NT - 2; kt2 += 2){
    TILE_F(0, bfX, bfY, 1, 1, 1, 1, 4, 4, 2);
    TILE_F(1, bfY, bfX, 1, 1, 1, 1, 4, 4, 2);
    pA += 128; pB += 128;
  }
  // kt = NT-2 (CB=0): stage tile NT-1 (no A-lo(kt+2)); read-ahead its frags;
  // drain everything at I3 so tile NT-1's I0 reads are safe.
  TILE_F(0, bfX, bfY, 1, 0, 1, 1, 4, 4, 0);
  // kt = NT-1 (CB=1): compute only.
  TILE_F(1, bfY, bfX, 0, 0, 0, 0, -1, -1, -1);
#undef TILE_F
#undef Q8
#undef RD_A
#undef RD_B

  // ---- epilogue: C/D layout col = lane&15, row = (lane>>4)*4 + r ----
  #pragma unroll
  for (int mf = 0; mf < 8; ++mf){
    const int row = m0 + wr * 128 + mf * 16 + q * 4;
    #pragma unroll
    for (int nf = 0; nf < 4; ++nf){
      const int col = n0 + wc * 64 + nf * 16 + c15;
      #pragma unroll
      for (int r = 0; r < 4; ++r){
        float v = acc[mf][nf][r];
        if constexpr (PHASE1){
          ((unsigned short*)Out)[(size_t)cp * M * Nd + (size_t)(row + r) * Nd + col] = f2b(gelu_fast(v));
        } else {
          ((float*)Out)[(size_t)p * M * Nd + (size_t)(row + r) * Nd + col] = v;
        }
      }
    }
  }
}

// ---------------- launch ----------------

extern "C" void kernel_launch(void* const* d_in, const int* in_sizes, int n_in,
                              void* d_out, int out_size, void* d_ws, size_t ws_size,
                              hipStream_t stream){
  const float* x  = (const float*)d_in[0];
  const float* w1 = (const float*)d_in[1];
  const float* b1 = (const float*)d_in[2];
  const float* w2 = (const float*)d_in[3];
  const float* b2 = (const float*)d_in[4];
  float* out = (float*)d_out;

  unsigned short* xb  = (unsigned short*)d_ws;
  unsigned short* w1t = (unsigned short*)((char*)d_ws + ((size_t)64  << 20));
  unsigned short* w2t = (unsigned short*)((char*)d_ws + ((size_t)128 << 20));
  unsigned short* hb  = (unsigned short*)((char*)d_ws + ((size_t)192 << 20));

  size_t avail = ws_size > ((size_t)192 << 20) ? ws_size - ((size_t)192 << 20) : 0;
  int ppc = (int)(avail / ((size_t)8 << 20));
  if (ppc > 32) ppc = 32;
  if (ppc < 1) return;

  cvt_x_kernel<<<2048, 256, 0, stream>>>(x, xb, 8 * 1024 * 1024);
  transpose_cvt<<<dim3(64, 16, 8), 256, 0, stream>>>(w1, w1t, 1024, 4096);
  transpose_cvt<<<dim3(16, 64, 8), 256, 0, stream>>>(w2, w2t, 4096, 1024);

  for (int p0 = 0; p0 < 32; p0 += ppc){
    int np = (32 - p0 < ppc) ? (32 - p0) : ppc;
    // GEMM1: h = gelu(xb @ w1t^T + b1)   [M=1024, K=1024, Nd=4096]
    gemm256<1><<<dim3(np * 4 * 16), 512, 0, stream>>>(xb, w1t, b1, hb, p0);
    // GEMM2: out = h @ w2t^T + b2        [M=1024, K=4096, Nd=1024]
    gemm256<0><<<dim3(np * 4 * 4),  512, 0, stream>>>(hb, w2t, b2, out, p0);
  }
}